// Round 1
// baseline (6612.964 us; speedup 1.0000x reference)
//
#include <hip/hip_runtime.h>
#include <hip/hip_bf16.h>

#define NUSERS 100000
#define NITEMS 50000
#define NNODES 150000
#define EMB 64
#define NLAYERS 3
#define NEDGES 2400000

// Build ego = concat(user_emb, item_emb) in ws, and write output cols 0..63.
__global__ __launch_bounds__(256) void init_kernel(
    const float* __restrict__ ue, const float* __restrict__ ie,
    float* __restrict__ ego, float* __restrict__ out)
{
    int i = blockIdx.x * 256 + threadIdx.x;   // float4 index over NNODES*16
    if (i >= NNODES * 16) return;
    int n = i >> 4, q = i & 15;
    float4 v = (n < NUSERS) ? ((const float4*)ue)[i]
                            : ((const float4*)ie)[i - NUSERS * 16];
    ((float4*)ego)[i] = v;
    *(float4*)(out + (size_t)n * 256 + q * 4) = v;
}

// side[r,:] += v * ego[c,:]  — 16 threads per edge, float4 gather, scalar atomics.
__global__ __launch_bounds__(256) void spmm_kernel(
    const int* __restrict__ rows, const int* __restrict__ cols,
    const float* __restrict__ vals, const float* __restrict__ ego,
    float* __restrict__ side)
{
    int t = blockIdx.x * 256 + threadIdx.x;
    int e = t >> 4;
    if (e >= NEDGES) return;
    int q = (t & 15) * 4;
    int r = rows[e], c = cols[e];
    float v = vals[e];
    float4 x = *(const float4*)(ego + (size_t)c * EMB + q);
    float* dst = side + (size_t)r * EMB + q;
    atomicAdd(dst + 0, v * x.x);
    atomicAdd(dst + 1, v * x.y);
    atomicAdd(dst + 2, v * x.z);
    atomicAdd(dst + 3, v * x.w);
}

// Per node: sum_emb = leaky(side@Wgc + bg); bi = leaky((ego*side)@Wbi + bb);
// ego_new = sum_emb + bi (stored back in-place); out = ego_new / max(||ego_new||,eps).
// One wave per node; weight columns held in VGPRs (lane j owns W[:,j]).
#define WPB 4
__global__ __launch_bounds__(256) void dense_kernel(
    const float* __restrict__ side, float* __restrict__ ego,
    const float* __restrict__ gw, const float* __restrict__ gb,
    const float* __restrict__ bw, const float* __restrict__ bb,
    float* __restrict__ out, int out_col0)
{
    __shared__ __align__(16) float lds_s[WPB * EMB];
    __shared__ __align__(16) float lds_p[WPB * EMB];
    const int j = threadIdx.x & 63;
    const int w = threadIdx.x >> 6;

    // Load W columns once per block (coalesced across lanes; hot in L1 after first block).
    float wg[EMB], wb2[EMB];
    #pragma unroll
    for (int k = 0; k < EMB; ++k) {
        wg[k]  = gw[k * EMB + j];
        wb2[k] = bw[k * EMB + j];
    }
    const float bg = gb[j], bbv = bb[j];

    const int stride = (int)gridDim.x * WPB;
    for (int n = (int)blockIdx.x * WPB + w; n < NNODES; n += stride) {
        const size_t base = (size_t)n * EMB;
        float s = side[base + j];
        float e = ego[base + j];
        // stage vectors in wave-private LDS for float4 broadcast reads
        lds_s[w * EMB + j] = s;
        lds_p[w * EMB + j] = s * e;
        __builtin_amdgcn_wave_barrier();   // DS ops in a wave complete in order; fence compiler motion

        float acc1 = bg, acc2 = bbv;
        const float4* s4 = (const float4*)(lds_s + w * EMB);
        const float4* p4 = (const float4*)(lds_p + w * EMB);
        #pragma unroll
        for (int kk = 0; kk < 16; ++kk) {
            float4 sv = s4[kk], pv = p4[kk];
            acc1 += sv.x * wg[4*kk+0] + sv.y * wg[4*kk+1]
                  + sv.z * wg[4*kk+2] + sv.w * wg[4*kk+3];
            acc2 += pv.x * wb2[4*kk+0] + pv.y * wb2[4*kk+1]
                  + pv.z * wb2[4*kk+2] + pv.w * wb2[4*kk+3];
        }

        float v1 = acc1 > 0.f ? acc1 : 0.01f * acc1;
        float v2 = acc2 > 0.f ? acc2 : 0.01f * acc2;
        float eg = v1 + v2;
        ego[base + j] = eg;

        float ss = eg * eg;
        #pragma unroll
        for (int off = 32; off; off >>= 1) ss += __shfl_xor(ss, off, 64);
        float inv = 1.0f / fmaxf(sqrtf(ss), 1e-12f);
        out[(size_t)n * 256 + out_col0 + j] = eg * inv;
        __builtin_amdgcn_wave_barrier();   // keep this iter's LDS reads before next iter's writes
    }
}

extern "C" void kernel_launch(void* const* d_in, const int* in_sizes, int n_in,
                              void* d_out, int out_size, void* d_ws, size_t ws_size,
                              hipStream_t stream)
{
    const int*   rows = (const int*)  d_in[0];
    const int*   cols = (const int*)  d_in[1];
    const float* vals = (const float*)d_in[2];
    const float* ue   = (const float*)d_in[3];
    const float* ie   = (const float*)d_in[4];
    const float* gw   = (const float*)d_in[5];
    const float* gb   = (const float*)d_in[6];
    const float* bw   = (const float*)d_in[7];
    const float* bb   = (const float*)d_in[8];
    float* out  = (float*)d_out;
    float* ego  = (float*)d_ws;                       // NNODES*EMB floats
    float* side = ego + (size_t)NNODES * EMB;         // NNODES*EMB floats

    init_kernel<<<(NNODES * 16 + 255) / 256, 256, 0, stream>>>(ue, ie, ego, out);

    for (int l = 0; l < NLAYERS; ++l) {
        hipMemsetAsync(side, 0, (size_t)NNODES * EMB * sizeof(float), stream);
        spmm_kernel<<<(NEDGES * 16 + 255) / 256, 256, 0, stream>>>(
            rows, cols, vals, ego, side);
        dense_kernel<<<2048, 256, 0, stream>>>(
            side, ego,
            gw + l * EMB * EMB, gb + l * EMB,
            bw + l * EMB * EMB, bb + l * EMB,
            out, 64 * (l + 1));
    }
}

// Round 2
// 1312.977 us; speedup vs baseline: 5.0366x; 5.0366x over previous
//
#include <hip/hip_runtime.h>
#include <hip/hip_bf16.h>

#define NUSERS 100000
#define NITEMS 50000
#define NNODES 150000
#define EMB 64
#define NLAYERS 3
#define NEDGES 2400000
#define SCAN_ITEMS 1024                      // items per scan block (256 thr x 4)
#define NSCAN_BLOCKS ((NNODES + SCAN_ITEMS - 1) / SCAN_ITEMS)   // 147

// ---------- CSR build (once per launch; adjacency identical for all layers) ----------

__global__ __launch_bounds__(256) void hist_kernel(
    const int* __restrict__ rows, int* __restrict__ deg)
{
    int e = blockIdx.x * 256 + threadIdx.x;
    if (e >= NEDGES) return;
    atomicAdd(&deg[rows[e]], 1);
}

__global__ __launch_bounds__(256) void block_sum_kernel(
    const int* __restrict__ deg, int* __restrict__ bsum)
{
    __shared__ int lds[256];
    int t = threadIdx.x;
    int base = blockIdx.x * SCAN_ITEMS + t * 4;
    int s = 0;
    #pragma unroll
    for (int k = 0; k < 4; ++k) {
        int idx = base + k;
        s += (idx < NNODES) ? deg[idx] : 0;
    }
    lds[t] = s; __syncthreads();
    for (int off = 128; off; off >>= 1) {
        if (t < off) lds[t] += lds[t + off];
        __syncthreads();
    }
    if (t == 0) bsum[blockIdx.x] = lds[0];
}

// single block: exclusive scan of the 147 block sums; also seals rowptr[N]
__global__ __launch_bounds__(256) void scan_partials_kernel(
    const int* __restrict__ bsum, int* __restrict__ bscan, int* __restrict__ rowptr)
{
    __shared__ int lds[256];
    int t = threadIdx.x;
    int v = (t < NSCAN_BLOCKS) ? bsum[t] : 0;
    lds[t] = v; __syncthreads();
    for (int off = 1; off < 256; off <<= 1) {
        int add = (t >= off) ? lds[t - off] : 0;
        __syncthreads();
        lds[t] += add;
        __syncthreads();
    }
    if (t < NSCAN_BLOCKS) bscan[t] = lds[t] - v;   // exclusive
    if (t == 0) rowptr[NNODES] = NEDGES;
}

__global__ __launch_bounds__(256) void block_scan_kernel(
    const int* __restrict__ deg, const int* __restrict__ bscan,
    int* __restrict__ rowptr, int* __restrict__ cursor)
{
    __shared__ int lds[256];
    int t = threadIdx.x;
    int base = blockIdx.x * SCAN_ITEMS + t * 4;
    int d[4]; int s = 0;
    #pragma unroll
    for (int k = 0; k < 4; ++k) {
        int idx = base + k;
        d[k] = (idx < NNODES) ? deg[idx] : 0;
        s += d[k];
    }
    lds[t] = s; __syncthreads();
    int v = s;
    for (int off = 1; off < 256; off <<= 1) {
        int add = (t >= off) ? lds[t - off] : 0;
        __syncthreads();
        lds[t] += add;
        __syncthreads();
    }
    int ex = lds[t] - v + bscan[blockIdx.x];
    #pragma unroll
    for (int k = 0; k < 4; ++k) {
        int idx = base + k;
        if (idx < NNODES) { rowptr[idx] = ex; cursor[idx] = ex; ex += d[k]; }
    }
}

// pack edge as {col, val} so the gather loop reads one 8B coalesced element
__global__ __launch_bounds__(256) void scatter_kernel(
    const int* __restrict__ rows, const int* __restrict__ cols,
    const float* __restrict__ vals, int* __restrict__ cursor,
    int2* __restrict__ edges)
{
    int e = blockIdx.x * 256 + threadIdx.x;
    if (e >= NEDGES) return;
    int pos = atomicAdd(&cursor[rows[e]], 1);
    edges[pos] = make_int2(cols[e], __float_as_int(vals[e]));
}

// ---------- ego init + output cols 0..63 ----------

__global__ __launch_bounds__(256) void init_kernel(
    const float* __restrict__ ue, const float* __restrict__ ie,
    float* __restrict__ ego, float* __restrict__ out)
{
    int i = blockIdx.x * 256 + threadIdx.x;   // float4 index over NNODES*16
    if (i >= NNODES * 16) return;
    int n = i >> 4, q = i & 15;
    float4 v = (n < NUSERS) ? ((const float4*)ue)[i]
                            : ((const float4*)ie)[i - NUSERS * 16];
    ((float4*)ego)[i] = v;
    *(float4*)(out + (size_t)n * 256 + q * 4) = v;
}

// ---------- fused pull-SpMM + dense + normalize, one wave per row ----------
// lane j owns element j of the row. Gather: coalesced 256B/edge from ego_in.
// Then dense via wave-private LDS broadcast with W columns in VGPRs.
__global__ __launch_bounds__(256) void layer_kernel(
    const int* __restrict__ rowptr, const int2* __restrict__ edges,
    const float* __restrict__ ego_in, float* __restrict__ ego_out,
    const float* __restrict__ gw, const float* __restrict__ gb,
    const float* __restrict__ bw, const float* __restrict__ bb,
    float* __restrict__ out, int out_col0)
{
    __shared__ __align__(16) float lds_s[4 * EMB];
    __shared__ __align__(16) float lds_p[4 * EMB];
    const int j = threadIdx.x & 63;
    const int w = threadIdx.x >> 6;

    float wg[EMB], wb2[EMB];
    #pragma unroll
    for (int k = 0; k < EMB; ++k) {
        wg[k]  = gw[k * EMB + j];
        wb2[k] = bw[k * EMB + j];
    }
    const float bg = gb[j], bbv = bb[j];

    const int stride = (int)gridDim.x * 4;
    for (int r = (int)blockIdx.x * 4 + w; r < NNODES; r += stride) {
        const int s = rowptr[r], epos = rowptr[r + 1];
        float e = ego_in[(size_t)r * EMB + j];   // hoisted: needed for bi term
        float acc0 = 0.f, acc1 = 0.f, acc2 = 0.f, acc3 = 0.f;

        for (int base = s; base < epos; base += 64) {
            int cnt = min(64, epos - base);
            int2 ed = (base + j < epos) ? edges[base + j] : make_int2(0, 0);
            int cl = ed.x; float vl = __int_as_float(ed.y);
            int i = 0;
            for (; i + 4 <= cnt; i += 4) {       // 4 independent gathers in flight
                int   c0 = __shfl(cl, i),     c1 = __shfl(cl, i + 1);
                int   c2 = __shfl(cl, i + 2), c3 = __shfl(cl, i + 3);
                float v0 = __shfl(vl, i),     v1 = __shfl(vl, i + 1);
                float v2 = __shfl(vl, i + 2), v3 = __shfl(vl, i + 3);
                acc0 += v0 * ego_in[(size_t)c0 * EMB + j];
                acc1 += v1 * ego_in[(size_t)c1 * EMB + j];
                acc2 += v2 * ego_in[(size_t)c2 * EMB + j];
                acc3 += v3 * ego_in[(size_t)c3 * EMB + j];
            }
            for (; i < cnt; ++i) {
                int c = __shfl(cl, i); float v = __shfl(vl, i);
                acc0 += v * ego_in[(size_t)c * EMB + j];
            }
        }
        float sde = (acc0 + acc1) + (acc2 + acc3);

        lds_s[w * EMB + j] = sde;
        lds_p[w * EMB + j] = sde * e;
        __builtin_amdgcn_wave_barrier();

        float a1 = bg, a2 = bbv;
        const float4* s4 = (const float4*)(lds_s + w * EMB);
        const float4* p4 = (const float4*)(lds_p + w * EMB);
        #pragma unroll
        for (int kk = 0; kk < 16; ++kk) {
            float4 sv = s4[kk], pv = p4[kk];
            a1 += sv.x * wg[4*kk+0] + sv.y * wg[4*kk+1]
                + sv.z * wg[4*kk+2] + sv.w * wg[4*kk+3];
            a2 += pv.x * wb2[4*kk+0] + pv.y * wb2[4*kk+1]
                + pv.z * wb2[4*kk+2] + pv.w * wb2[4*kk+3];
        }

        float v1 = a1 > 0.f ? a1 : 0.01f * a1;
        float v2 = a2 > 0.f ? a2 : 0.01f * a2;
        float eg = v1 + v2;
        ego_out[(size_t)r * EMB + j] = eg;

        float ss = eg * eg;
        #pragma unroll
        for (int off = 32; off; off >>= 1) ss += __shfl_xor(ss, off, 64);
        float inv = 1.0f / fmaxf(sqrtf(ss), 1e-12f);
        out[(size_t)r * 256 + out_col0 + j] = eg * inv;
        __builtin_amdgcn_wave_barrier();
    }
}

extern "C" void kernel_launch(void* const* d_in, const int* in_sizes, int n_in,
                              void* d_out, int out_size, void* d_ws, size_t ws_size,
                              hipStream_t stream)
{
    const int*   rows = (const int*)  d_in[0];
    const int*   cols = (const int*)  d_in[1];
    const float* vals = (const float*)d_in[2];
    const float* ue   = (const float*)d_in[3];
    const float* ie   = (const float*)d_in[4];
    const float* gw   = (const float*)d_in[5];
    const float* gb   = (const float*)d_in[6];
    const float* bw   = (const float*)d_in[7];
    const float* bb   = (const float*)d_in[8];
    float* out = (float*)d_out;

    // ---- workspace layout (~97.8 MB) ----
    char* p = (char*)d_ws;
    float* ego_a  = (float*)p;                 p += (size_t)NNODES * EMB * 4;   // 38.4 MB
    float* ego_b  = (float*)p;                 p += (size_t)NNODES * EMB * 4;   // 38.4 MB
    int2*  edges  = (int2*)p;                  p += (size_t)NEDGES * 8;         // 19.2 MB
    int*   rowptr = (int*)p;                   p += ((size_t)NNODES + 4) * 4;
    int*   deg    = (int*)p;                   p += (size_t)NNODES * 4;
    int*   cursor = (int*)p;                   p += (size_t)NNODES * 4;
    int*   bsum   = (int*)p;                   p += 1024;
    int*   bscan  = (int*)p;                   p += 1024;

    // ---- CSR build (once; same adjacency for all 3 layers) ----
    hipMemsetAsync(deg, 0, (size_t)NNODES * 4, stream);
    hist_kernel<<<(NEDGES + 255) / 256, 256, 0, stream>>>(rows, deg);
    block_sum_kernel<<<NSCAN_BLOCKS, 256, 0, stream>>>(deg, bsum);
    scan_partials_kernel<<<1, 256, 0, stream>>>(bsum, bscan, rowptr);
    block_scan_kernel<<<NSCAN_BLOCKS, 256, 0, stream>>>(deg, bscan, rowptr, cursor);
    scatter_kernel<<<(NEDGES + 255) / 256, 256, 0, stream>>>(rows, cols, vals, cursor, edges);

    init_kernel<<<(NNODES * 16 + 255) / 256, 256, 0, stream>>>(ue, ie, ego_a, out);

    float* cur = ego_a;
    float* nxt = ego_b;
    for (int l = 0; l < NLAYERS; ++l) {
        layer_kernel<<<2048, 256, 0, stream>>>(
            rowptr, edges, cur, nxt,
            gw + l * EMB * EMB, gb + l * EMB,
            bw + l * EMB * EMB, bb + l * EMB,
            out, 64 * (l + 1));
        float* t = cur; cur = nxt; nxt = t;
    }
}

// Round 3
// 963.596 us; speedup vs baseline: 6.8628x; 1.3626x over previous
//
#include <hip/hip_runtime.h>
#include <hip/hip_bf16.h>

#define NUSERS 100000
#define NITEMS 50000
#define NNODES 150000
#define EMB 64
#define NLAYERS 3
#define NEDGES 2400000
#define SCAN_ITEMS 1024                      // items per scan block (256 thr x 4)
#define NSCAN_BLOCKS ((NNODES + SCAN_ITEMS - 1) / SCAN_ITEMS)   // 147

// ---------- CSR build (once per launch; adjacency identical for all layers) ----------

// histogram + per-edge rank capture in ONE atomic pass
__global__ __launch_bounds__(256) void hist_rank_kernel(
    const int* __restrict__ rows, int* __restrict__ deg, int* __restrict__ rank)
{
    int e = blockIdx.x * 256 + threadIdx.x;
    if (e >= NEDGES) return;
    rank[e] = atomicAdd(&deg[rows[e]], 1);
}

__global__ __launch_bounds__(256) void block_sum_kernel(
    const int* __restrict__ deg, int* __restrict__ bsum)
{
    __shared__ int lds[256];
    int t = threadIdx.x;
    int base = blockIdx.x * SCAN_ITEMS + t * 4;
    int s = 0;
    #pragma unroll
    for (int k = 0; k < 4; ++k) {
        int idx = base + k;
        s += (idx < NNODES) ? deg[idx] : 0;
    }
    lds[t] = s; __syncthreads();
    for (int off = 128; off; off >>= 1) {
        if (t < off) lds[t] += lds[t + off];
        __syncthreads();
    }
    if (t == 0) bsum[blockIdx.x] = lds[0];
}

// single block: exclusive scan of the 147 block sums; also seals rowptr[N]
__global__ __launch_bounds__(256) void scan_partials_kernel(
    const int* __restrict__ bsum, int* __restrict__ bscan, int* __restrict__ rowptr)
{
    __shared__ int lds[256];
    int t = threadIdx.x;
    int v = (t < NSCAN_BLOCKS) ? bsum[t] : 0;
    lds[t] = v; __syncthreads();
    for (int off = 1; off < 256; off <<= 1) {
        int add = (t >= off) ? lds[t - off] : 0;
        __syncthreads();
        lds[t] += add;
        __syncthreads();
    }
    if (t < NSCAN_BLOCKS) bscan[t] = lds[t] - v;   // exclusive
    if (t == 0) rowptr[NNODES] = NEDGES;
}

__global__ __launch_bounds__(256) void block_scan_kernel(
    const int* __restrict__ deg, const int* __restrict__ bscan,
    int* __restrict__ rowptr)
{
    __shared__ int lds[256];
    int t = threadIdx.x;
    int base = blockIdx.x * SCAN_ITEMS + t * 4;
    int d[4]; int s = 0;
    #pragma unroll
    for (int k = 0; k < 4; ++k) {
        int idx = base + k;
        d[k] = (idx < NNODES) ? deg[idx] : 0;
        s += d[k];
    }
    lds[t] = s; __syncthreads();
    int v = s;
    for (int off = 1; off < 256; off <<= 1) {
        int add = (t >= off) ? lds[t - off] : 0;
        __syncthreads();
        lds[t] += add;
        __syncthreads();
    }
    int ex = lds[t] - v + bscan[blockIdx.x];
    #pragma unroll
    for (int k = 0; k < 4; ++k) {
        int idx = base + k;
        if (idx < NNODES) { rowptr[idx] = ex; ex += d[k]; }
    }
}

// atomic-free scatter: pos = rowptr[row] + rank; pack {col, val} for 8B gather reads
__global__ __launch_bounds__(256) void scatter_kernel(
    const int* __restrict__ rows, const int* __restrict__ cols,
    const float* __restrict__ vals, const int* __restrict__ rank,
    const int* __restrict__ rowptr, int2* __restrict__ edges)
{
    int e = blockIdx.x * 256 + threadIdx.x;
    if (e >= NEDGES) return;
    int pos = rowptr[rows[e]] + rank[e];
    edges[pos] = make_int2(cols[e], __float_as_int(vals[e]));
}

// ---------- ego init + output cols 0..63 ----------

__global__ __launch_bounds__(256) void init_kernel(
    const float* __restrict__ ue, const float* __restrict__ ie,
    float* __restrict__ ego, float* __restrict__ out)
{
    int i = blockIdx.x * 256 + threadIdx.x;   // float4 index over NNODES*16
    if (i >= NNODES * 16) return;
    int n = i >> 4, q = i & 15;
    float4 v = (n < NUSERS) ? ((const float4*)ue)[i]
                            : ((const float4*)ie)[i - NUSERS * 16];
    ((float4*)ego)[i] = v;
    *(float4*)(out + (size_t)n * 256 + q * 4) = v;
}

// ---------- pull-mode SpMM: side = A @ ego. One wave per row, minimal VGPR ----------
// lane j owns element j. 8 independent gathers in flight for MLP.
__global__ __launch_bounds__(256) void spmm_pull(
    const int* __restrict__ rowptr, const int2* __restrict__ edges,
    const float* __restrict__ ego, float* __restrict__ side)
{
    const int j = threadIdx.x & 63;
    const int w = threadIdx.x >> 6;
    const int stride = (int)gridDim.x * 4;
    for (int r = (int)blockIdx.x * 4 + w; r < NNODES; r += stride) {
        const int s = rowptr[r], e = rowptr[r + 1];
        float a0 = 0.f, a1 = 0.f, a2 = 0.f, a3 = 0.f;
        float a4 = 0.f, a5 = 0.f, a6 = 0.f, a7 = 0.f;
        for (int base = s; base < e; base += 64) {
            int cnt = min(64, e - base);
            int2 ed = (base + j < e) ? edges[base + j] : make_int2(0, 0);
            int cl = ed.x; float vl = __int_as_float(ed.y);
            int i = 0;
            for (; i + 8 <= cnt; i += 8) {          // 8 loads in flight
                int   c0 = __shfl(cl, i + 0, 64), c1 = __shfl(cl, i + 1, 64);
                int   c2 = __shfl(cl, i + 2, 64), c3 = __shfl(cl, i + 3, 64);
                int   c4 = __shfl(cl, i + 4, 64), c5 = __shfl(cl, i + 5, 64);
                int   c6 = __shfl(cl, i + 6, 64), c7 = __shfl(cl, i + 7, 64);
                float v0 = __shfl(vl, i + 0, 64), v1 = __shfl(vl, i + 1, 64);
                float v2 = __shfl(vl, i + 2, 64), v3 = __shfl(vl, i + 3, 64);
                float v4 = __shfl(vl, i + 4, 64), v5 = __shfl(vl, i + 5, 64);
                float v6 = __shfl(vl, i + 6, 64), v7 = __shfl(vl, i + 7, 64);
                a0 += v0 * ego[c0 * EMB + j];
                a1 += v1 * ego[c1 * EMB + j];
                a2 += v2 * ego[c2 * EMB + j];
                a3 += v3 * ego[c3 * EMB + j];
                a4 += v4 * ego[c4 * EMB + j];
                a5 += v5 * ego[c5 * EMB + j];
                a6 += v6 * ego[c6 * EMB + j];
                a7 += v7 * ego[c7 * EMB + j];
            }
            for (; i < cnt; ++i) {
                int c = __shfl(cl, i, 64); float v = __shfl(vl, i, 64);
                a0 += v * ego[c * EMB + j];
            }
        }
        side[(size_t)r * EMB + j] = ((a0 + a1) + (a2 + a3)) + ((a4 + a5) + (a6 + a7));
    }
}

// ---------- dense + leaky + in-place ego update + L2-normalize ----------
#define WPB 4
__global__ __launch_bounds__(256) void dense_kernel(
    const float* __restrict__ side, float* __restrict__ ego,
    const float* __restrict__ gw, const float* __restrict__ gb,
    const float* __restrict__ bw, const float* __restrict__ bb,
    float* __restrict__ out, int out_col0)
{
    __shared__ __align__(16) float lds_s[WPB * EMB];
    __shared__ __align__(16) float lds_p[WPB * EMB];
    const int j = threadIdx.x & 63;
    const int w = threadIdx.x >> 6;

    float wg[EMB], wb2[EMB];
    #pragma unroll
    for (int k = 0; k < EMB; ++k) {
        wg[k]  = gw[k * EMB + j];
        wb2[k] = bw[k * EMB + j];
    }
    const float bg = gb[j], bbv = bb[j];

    const int stride = (int)gridDim.x * WPB;
    for (int n = (int)blockIdx.x * WPB + w; n < NNODES; n += stride) {
        const size_t base = (size_t)n * EMB;
        float s = side[base + j];
        float e = ego[base + j];
        lds_s[w * EMB + j] = s;
        lds_p[w * EMB + j] = s * e;
        __builtin_amdgcn_wave_barrier();

        float a1 = bg, a2 = bbv;
        const float4* s4 = (const float4*)(lds_s + w * EMB);
        const float4* p4 = (const float4*)(lds_p + w * EMB);
        #pragma unroll
        for (int kk = 0; kk < 16; ++kk) {
            float4 sv = s4[kk], pv = p4[kk];
            a1 += sv.x * wg[4*kk+0] + sv.y * wg[4*kk+1]
                + sv.z * wg[4*kk+2] + sv.w * wg[4*kk+3];
            a2 += pv.x * wb2[4*kk+0] + pv.y * wb2[4*kk+1]
                + pv.z * wb2[4*kk+2] + pv.w * wb2[4*kk+3];
        }

        float v1 = a1 > 0.f ? a1 : 0.01f * a1;
        float v2 = a2 > 0.f ? a2 : 0.01f * a2;
        float eg = v1 + v2;
        ego[base + j] = eg;               // in-place: row-local update

        float ss = eg * eg;
        #pragma unroll
        for (int off = 32; off; off >>= 1) ss += __shfl_xor(ss, off, 64);
        float inv = 1.0f / fmaxf(sqrtf(ss), 1e-12f);
        out[(size_t)n * 256 + out_col0 + j] = eg * inv;
        __builtin_amdgcn_wave_barrier();
    }
}

extern "C" void kernel_launch(void* const* d_in, const int* in_sizes, int n_in,
                              void* d_out, int out_size, void* d_ws, size_t ws_size,
                              hipStream_t stream)
{
    const int*   rows = (const int*)  d_in[0];
    const int*   cols = (const int*)  d_in[1];
    const float* vals = (const float*)d_in[2];
    const float* ue   = (const float*)d_in[3];
    const float* ie   = (const float*)d_in[4];
    const float* gw   = (const float*)d_in[5];
    const float* gb   = (const float*)d_in[6];
    const float* bw   = (const float*)d_in[7];
    const float* bb   = (const float*)d_in[8];
    float* out = (float*)d_out;

    // ---- workspace layout (~96.6 MB) ----
    char* p = (char*)d_ws;
    float* ego    = (float*)p;   p += (size_t)NNODES * EMB * 4;   // 38.4 MB
    float* side   = (float*)p;   p += (size_t)NNODES * EMB * 4;   // 38.4 MB
    int2*  edges  = (int2*)p;    p += (size_t)NEDGES * 8;         // 19.2 MB
    int*   rowptr = (int*)p;     p += ((size_t)NNODES + 4) * 4;   // 0.6 MB
    // build-time scratch aliased into the side region (side is rewritten each layer)
    int*   deg    = (int*)side;                       // 0.6 MB
    int*   rank   = (int*)side + NNODES;              // 9.6 MB
    int*   bsum   = (int*)side + NNODES + NEDGES;
    int*   bscan  = bsum + 256;

    // ---- CSR build (once; same adjacency for all 3 layers) ----
    hipMemsetAsync(deg, 0, (size_t)NNODES * 4, stream);
    hist_rank_kernel<<<(NEDGES + 255) / 256, 256, 0, stream>>>(rows, deg, rank);
    block_sum_kernel<<<NSCAN_BLOCKS, 256, 0, stream>>>(deg, bsum);
    scan_partials_kernel<<<1, 256, 0, stream>>>(bsum, bscan, rowptr);
    block_scan_kernel<<<NSCAN_BLOCKS, 256, 0, stream>>>(deg, bscan, rowptr);
    scatter_kernel<<<(NEDGES + 255) / 256, 256, 0, stream>>>(
        rows, cols, vals, rank, rowptr, edges);

    init_kernel<<<(NNODES * 16 + 255) / 256, 256, 0, stream>>>(ue, ie, ego, out);

    for (int l = 0; l < NLAYERS; ++l) {
        spmm_pull<<<4096, 256, 0, stream>>>(rowptr, edges, ego, side);
        dense_kernel<<<2048, 256, 0, stream>>>(
            side, ego,
            gw + l * EMB * EMB, gb + l * EMB,
            bw + l * EMB * EMB, bb + l * EMB,
            out, 64 * (l + 1));
    }
}

// Round 4
// 658.767 us; speedup vs baseline: 10.0384x; 1.4627x over previous
//
#include <hip/hip_runtime.h>
#include <hip/hip_bf16.h>

#define NUSERS 100000
#define NITEMS 50000
#define NNODES 150000
#define EMB 64
#define NLAYERS 3
#define NEDGES 2400000
#define SCAN_ITEMS 1024
#define NSCAN_BLOCKS ((NNODES + SCAN_ITEMS - 1) / SCAN_ITEMS)   // 147
#define NTILES (NNODES / 16)                                    // 9375

typedef __attribute__((ext_vector_type(8))) short short8;
typedef __attribute__((ext_vector_type(4))) float float4v;

__device__ __forceinline__ float bf2f(unsigned short u) {
    return __uint_as_float((unsigned int)u << 16);
}
__device__ __forceinline__ unsigned short f2bf(float f) {
    unsigned int x = __float_as_uint(f);
    return (unsigned short)((x + 0x7FFFu + ((x >> 16) & 1u)) >> 16);   // RNE
}

// ---------- CSR build (once; adjacency identical for all layers) ----------

__global__ __launch_bounds__(256) void hist_rank_kernel(
    const int* __restrict__ rows, int* __restrict__ deg, int* __restrict__ rank)
{
    int e = blockIdx.x * 256 + threadIdx.x;
    if (e >= NEDGES) return;
    rank[e] = atomicAdd(&deg[rows[e]], 1);
}

__global__ __launch_bounds__(256) void block_sum_kernel(
    const int* __restrict__ deg, int* __restrict__ bsum)
{
    __shared__ int lds[256];
    int t = threadIdx.x;
    int base = blockIdx.x * SCAN_ITEMS + t * 4;
    int s = 0;
    #pragma unroll
    for (int k = 0; k < 4; ++k) {
        int idx = base + k;
        s += (idx < NNODES) ? deg[idx] : 0;
    }
    lds[t] = s; __syncthreads();
    for (int off = 128; off; off >>= 1) {
        if (t < off) lds[t] += lds[t + off];
        __syncthreads();
    }
    if (t == 0) bsum[blockIdx.x] = lds[0];
}

__global__ __launch_bounds__(256) void scan_partials_kernel(
    const int* __restrict__ bsum, int* __restrict__ bscan, int* __restrict__ rowptr)
{
    __shared__ int lds[256];
    int t = threadIdx.x;
    int v = (t < NSCAN_BLOCKS) ? bsum[t] : 0;
    lds[t] = v; __syncthreads();
    for (int off = 1; off < 256; off <<= 1) {
        int add = (t >= off) ? lds[t - off] : 0;
        __syncthreads();
        lds[t] += add;
        __syncthreads();
    }
    if (t < NSCAN_BLOCKS) bscan[t] = lds[t] - v;
    if (t == 0) rowptr[NNODES] = NEDGES;
}

__global__ __launch_bounds__(256) void block_scan_kernel(
    const int* __restrict__ deg, const int* __restrict__ bscan,
    int* __restrict__ rowptr)
{
    __shared__ int lds[256];
    int t = threadIdx.x;
    int base = blockIdx.x * SCAN_ITEMS + t * 4;
    int d[4]; int s = 0;
    #pragma unroll
    for (int k = 0; k < 4; ++k) {
        int idx = base + k;
        d[k] = (idx < NNODES) ? deg[idx] : 0;
        s += d[k];
    }
    lds[t] = s; __syncthreads();
    int v = s;
    for (int off = 1; off < 256; off <<= 1) {
        int add = (t >= off) ? lds[t - off] : 0;
        __syncthreads();
        lds[t] += add;
        __syncthreads();
    }
    int ex = lds[t] - v + bscan[blockIdx.x];
    #pragma unroll
    for (int k = 0; k < 4; ++k) {
        int idx = base + k;
        if (idx < NNODES) { rowptr[idx] = ex; ex += d[k]; }
    }
}

__global__ __launch_bounds__(256) void scatter_kernel(
    const int* __restrict__ rows, const int* __restrict__ cols,
    const float* __restrict__ vals, const int* __restrict__ rank,
    const int* __restrict__ rowptr, int2* __restrict__ edges)
{
    int e = blockIdx.x * 256 + threadIdx.x;
    if (e >= NEDGES) return;
    int pos = rowptr[rows[e]] + rank[e];
    edges[pos] = make_int2(cols[e], __float_as_int(vals[e]));
}

// ---------- weight fp32 -> bf16 (once) ----------
__global__ __launch_bounds__(256) void wconv_kernel(
    const float* __restrict__ gw, const float* __restrict__ bw,
    unsigned short* __restrict__ wg_bf, unsigned short* __restrict__ wb_bf)
{
    int i = blockIdx.x * 256 + threadIdx.x;
    if (i >= NLAYERS * EMB * EMB) return;
    wg_bf[i] = f2bf(gw[i]);
    wb_bf[i] = f2bf(bw[i]);
}

// ---------- ego init (bf16) + output cols 0..63 (fp32) ----------
__global__ __launch_bounds__(256) void init_kernel(
    const float* __restrict__ ue, const float* __restrict__ ie,
    unsigned short* __restrict__ ego_bf, float* __restrict__ out)
{
    int i = blockIdx.x * 256 + threadIdx.x;   // float4 index over NNODES*16
    if (i >= NNODES * 16) return;
    int n = i >> 4, q = i & 15;
    float4 v = (n < NUSERS) ? ((const float4*)ue)[i]
                            : ((const float4*)ie)[i - NUSERS * 16];
    *(float4*)(out + (size_t)n * 256 + q * 4) = v;
    ushort4 b;
    b.x = f2bf(v.x); b.y = f2bf(v.y); b.z = f2bf(v.z); b.w = f2bf(v.w);
    *(ushort4*)(ego_bf + (size_t)n * EMB + q * 4) = b;
}

// ---------- pull-mode SpMM: side = A @ ego, bf16 storage, fp32 accum ----------
__global__ __launch_bounds__(256) void spmm_pull(
    const int* __restrict__ rowptr, const int2* __restrict__ edges,
    const unsigned short* __restrict__ ego_bf, unsigned short* __restrict__ side_bf)
{
    const int j = threadIdx.x & 63;
    const int w = threadIdx.x >> 6;
    const int stride = (int)gridDim.x * 4;
    for (int r = (int)blockIdx.x * 4 + w; r < NNODES; r += stride) {
        const int s = rowptr[r], e = rowptr[r + 1];
        float a0 = 0.f, a1 = 0.f, a2 = 0.f, a3 = 0.f;
        float a4 = 0.f, a5 = 0.f, a6 = 0.f, a7 = 0.f;
        for (int base = s; base < e; base += 64) {
            int cnt = min(64, e - base);
            int2 ed = (base + j < e) ? edges[base + j] : make_int2(0, 0);
            int cl = ed.x; float vl = __int_as_float(ed.y);
            int i = 0;
            for (; i + 8 <= cnt; i += 8) {          // 8 gathers in flight
                int   c0 = __shfl(cl, i + 0, 64), c1 = __shfl(cl, i + 1, 64);
                int   c2 = __shfl(cl, i + 2, 64), c3 = __shfl(cl, i + 3, 64);
                int   c4 = __shfl(cl, i + 4, 64), c5 = __shfl(cl, i + 5, 64);
                int   c6 = __shfl(cl, i + 6, 64), c7 = __shfl(cl, i + 7, 64);
                float v0 = __shfl(vl, i + 0, 64), v1 = __shfl(vl, i + 1, 64);
                float v2 = __shfl(vl, i + 2, 64), v3 = __shfl(vl, i + 3, 64);
                float v4 = __shfl(vl, i + 4, 64), v5 = __shfl(vl, i + 5, 64);
                float v6 = __shfl(vl, i + 6, 64), v7 = __shfl(vl, i + 7, 64);
                a0 += v0 * bf2f(ego_bf[c0 * EMB + j]);
                a1 += v1 * bf2f(ego_bf[c1 * EMB + j]);
                a2 += v2 * bf2f(ego_bf[c2 * EMB + j]);
                a3 += v3 * bf2f(ego_bf[c3 * EMB + j]);
                a4 += v4 * bf2f(ego_bf[c4 * EMB + j]);
                a5 += v5 * bf2f(ego_bf[c5 * EMB + j]);
                a6 += v6 * bf2f(ego_bf[c6 * EMB + j]);
                a7 += v7 * bf2f(ego_bf[c7 * EMB + j]);
            }
            for (; i < cnt; ++i) {
                int c = __shfl(cl, i, 64); float v = __shfl(vl, i, 64);
                a0 += v * bf2f(ego_bf[c * EMB + j]);
            }
        }
        float sum = ((a0 + a1) + (a2 + a3)) + ((a4 + a5) + (a6 + a7));
        side_bf[(size_t)r * EMB + j] = f2bf(sum);
    }
}

// ---------- MFMA dense: leaky(S@Wg+bg) + leaky((E*S)@Wb+bb), update ego, normalize ----------
// One wave per 16-row tile. 16x16x32 bf16 MFMA:
//   A[m=lane&15][k=(lane>>4)*8+j]; C/D: col=lane&15, row=(lane>>4)*4+reg.
__global__ __launch_bounds__(256) void dense_mfma(
    const unsigned short* __restrict__ side_bf, unsigned short* __restrict__ ego_bf,
    const unsigned short* __restrict__ wg_bf, const unsigned short* __restrict__ wb_bf,
    const float* __restrict__ gb, const float* __restrict__ bb,
    float* __restrict__ out, int out_col0)
{
    const int lane = threadIdx.x & 63;
    const int w    = threadIdx.x >> 6;
    const int m    = lane & 15;     // row (A) / col (B, C)
    const int q    = lane >> 4;     // quad

    const int t = (int)blockIdx.x * 4 + w;     // 16-row tile index
    if (t >= NTILES) return;

    // ---- B fragments: [n0][kh], lane j holds B[k=kh*32+q*8+j][n=n0*16+m]
    short8 bg[4][2], bbf[4][2];
    #pragma unroll
    for (int n0 = 0; n0 < 4; ++n0) {
        #pragma unroll
        for (int kh = 0; kh < 2; ++kh) {
            #pragma unroll
            for (int jj = 0; jj < 8; ++jj) {
                int k = kh * 32 + q * 8 + jj;
                int n = n0 * 16 + m;
                bg [n0][kh][jj] = (short)wg_bf[k * EMB + n];
                bbf[n0][kh][jj] = (short)wb_bf[k * EMB + n];
            }
        }
    }
    float bgc[4], bbc[4];
    #pragma unroll
    for (int n0 = 0; n0 < 4; ++n0) { bgc[n0] = gb[n0 * 16 + m]; bbc[n0] = bb[n0 * 16 + m]; }

    // ---- A fragments: rows t*16 .. t*16+15
    const size_t base = (size_t)t * 16 * EMB;
    const int ao = m * EMB + q * 8;
    short8 as0 = *(const short8*)(side_bf + base + ao);
    short8 as1 = *(const short8*)(side_bf + base + ao + 32);
    short8 ae0 = *(const short8*)(ego_bf  + base + ao);
    short8 ae1 = *(const short8*)(ego_bf  + base + ao + 32);
    short8 ap0, ap1;
    #pragma unroll
    for (int jj = 0; jj < 8; ++jj) {
        ap0[jj] = (short)f2bf(bf2f((unsigned short)as0[jj]) * bf2f((unsigned short)ae0[jj]));
        ap1[jj] = (short)f2bf(bf2f((unsigned short)as1[jj]) * bf2f((unsigned short)ae1[jj]));
    }

    // ---- MFMAs
    float4v c1[4], c2[4];
    #pragma unroll
    for (int n0 = 0; n0 < 4; ++n0) { c1[n0] = (float4v)0.f; c2[n0] = (float4v)0.f; }
    #pragma unroll
    for (int n0 = 0; n0 < 4; ++n0) {
        c1[n0] = __builtin_amdgcn_mfma_f32_16x16x32_bf16(as0, bg [n0][0], c1[n0], 0, 0, 0);
        c1[n0] = __builtin_amdgcn_mfma_f32_16x16x32_bf16(as1, bg [n0][1], c1[n0], 0, 0, 0);
        c2[n0] = __builtin_amdgcn_mfma_f32_16x16x32_bf16(ap0, bbf[n0][0], c2[n0], 0, 0, 0);
        c2[n0] = __builtin_amdgcn_mfma_f32_16x16x32_bf16(ap1, bbf[n0][1], c2[n0], 0, 0, 0);
    }

    // ---- epilogue: bias + leaky + ego update + L2 norm
    float eg[4][4];          // [n0][reg]; row = t*16 + q*4 + reg, col = n0*16 + m
    float ss[4] = {0.f, 0.f, 0.f, 0.f};
    #pragma unroll
    for (int n0 = 0; n0 < 4; ++n0) {
        #pragma unroll
        for (int r = 0; r < 4; ++r) {
            float a1 = c1[n0][r] + bgc[n0];
            float a2 = c2[n0][r] + bbc[n0];
            float v1 = a1 > 0.f ? a1 : 0.01f * a1;
            float v2 = a2 > 0.f ? a2 : 0.01f * a2;
            float e = v1 + v2;
            eg[n0][r] = e;
            ss[r] += e * e;
        }
    }
    #pragma unroll
    for (int r = 0; r < 4; ++r) {
        float s = ss[r];
        s += __shfl_xor(s, 1, 64);
        s += __shfl_xor(s, 2, 64);
        s += __shfl_xor(s, 4, 64);
        s += __shfl_xor(s, 8, 64);
        ss[r] = 1.0f / fmaxf(sqrtf(s), 1e-12f);
    }
    #pragma unroll
    for (int r = 0; r < 4; ++r) {
        int row = t * 16 + q * 4 + r;
        #pragma unroll
        for (int n0 = 0; n0 < 4; ++n0) {
            int col = n0 * 16 + m;
            ego_bf[(size_t)row * EMB + col] = f2bf(eg[n0][r]);
            out[(size_t)row * 256 + out_col0 + col] = eg[n0][r] * ss[r];
        }
    }
}

extern "C" void kernel_launch(void* const* d_in, const int* in_sizes, int n_in,
                              void* d_out, int out_size, void* d_ws, size_t ws_size,
                              hipStream_t stream)
{
    const int*   rows = (const int*)  d_in[0];
    const int*   cols = (const int*)  d_in[1];
    const float* vals = (const float*)d_in[2];
    const float* ue   = (const float*)d_in[3];
    const float* ie   = (const float*)d_in[4];
    const float* gw   = (const float*)d_in[5];
    const float* gb   = (const float*)d_in[6];
    const float* bw   = (const float*)d_in[7];
    const float* bb   = (const float*)d_in[8];
    float* out = (float*)d_out;

    // ---- workspace layout (~58.3 MB) ----
    char* p = (char*)d_ws;
    unsigned short* ego_bf  = (unsigned short*)p;  p += (size_t)NNODES * EMB * 2;  // 19.2 MB
    unsigned short* side_bf = (unsigned short*)p;  p += (size_t)NNODES * EMB * 2;  // 19.2 MB
    int2*  edges  = (int2*)p;    p += (size_t)NEDGES * 8;                          // 19.2 MB
    int*   rowptr = (int*)p;     p += ((size_t)NNODES + 4) * 4;                    // 0.6 MB
    unsigned short* wg_bf = (unsigned short*)p;  p += (size_t)NLAYERS * EMB * EMB * 2;
    unsigned short* wb_bf = (unsigned short*)p;  p += (size_t)NLAYERS * EMB * EMB * 2;
    // build scratch aliased into side region (10.2 MB < 19.2 MB; side rewritten each layer)
    int* deg   = (int*)side_bf;
    int* rank  = (int*)side_bf + NNODES;
    int* bsum  = (int*)side_bf + NNODES + NEDGES;
    int* bscan = bsum + 256;

    // ---- CSR build ----
    hipMemsetAsync(deg, 0, (size_t)NNODES * 4, stream);
    hist_rank_kernel<<<(NEDGES + 255) / 256, 256, 0, stream>>>(rows, deg, rank);
    block_sum_kernel<<<NSCAN_BLOCKS, 256, 0, stream>>>(deg, bsum);
    scan_partials_kernel<<<1, 256, 0, stream>>>(bsum, bscan, rowptr);
    block_scan_kernel<<<NSCAN_BLOCKS, 256, 0, stream>>>(deg, bscan, rowptr);
    scatter_kernel<<<(NEDGES + 255) / 256, 256, 0, stream>>>(
        rows, cols, vals, rank, rowptr, edges);

    wconv_kernel<<<(NLAYERS * EMB * EMB + 255) / 256, 256, 0, stream>>>(gw, bw, wg_bf, wb_bf);
    init_kernel<<<(NNODES * 16 + 255) / 256, 256, 0, stream>>>(ue, ie, ego_bf, out);

    for (int l = 0; l < NLAYERS; ++l) {
        spmm_pull<<<4096, 256, 0, stream>>>(rowptr, edges, ego_bf, side_bf);
        dense_mfma<<<(NTILES + 3) / 4, 256, 0, stream>>>(
            side_bf, ego_bf,
            wg_bf + l * EMB * EMB, wb_bf + l * EMB * EMB,
            gb + l * EMB, bb + l * EMB,
            out, 64 * (l + 1));
    }
}